// Round 4
// baseline (555.602 us; speedup 1.0000x reference)
//
#include <hip/hip_runtime.h>
#include <hip/hip_bf16.h>

// Problem constants
#define D_ 512
#define M_ 128
#define H_ 32
#define NT_ 160            // M_+H_: concatenated output cols
#define P_ 32              // points per block
#define NPTS_ 65536        // N
#define OPAD_ 165          // out LDS row stride in floats (stride%32=5 -> conflict-free transpose)
#define BLKS_PER_B 2048    // N / P_

// LDS map (49,280 B total -> 3 blocks/CU):
//   [0,      32768)  nx bf16, 32 rows x 1024 B, XOR-swizzled (epilogue f32 tile unions here)
//   [32768,  49152)  x f32 stage: 4 waves x 4096 B (2 rows each round)
//   [49152,  49280)  tau
#define NX_OFF    0
#define STAGE_OFF 32768
#define TAU_OFF   49152
#define LDS_BYTES 49280

typedef __attribute__((ext_vector_type(8))) short bf16x8;
typedef __attribute__((ext_vector_type(4))) short short4v;
typedef __attribute__((ext_vector_type(4))) float f32x4;

__device__ __forceinline__ short bf16bits(float f) {
    __hip_bfloat16 h = __float2bfloat16(f);
    return *reinterpret_cast<short*>(&h);
}

// Hardware-queued global->LDS copy: 16 B/lane, zero VGPR data registers, cannot be
// re-sunk by the register allocator (the round-0/3 failure mode: VGPR=52 proved the
// compiler serializes register-staged x loads into dependent HBM round trips).
#define GLOAD_LDS(gsrc, ldst)                                                        \
    __builtin_amdgcn_global_load_lds(                                                \
        (const __attribute__((address_space(1))) void*)(gsrc),                       \
        (__attribute__((address_space(3))) void*)(ldst), 16, 0, 0)

// Convert W_lin (128x512) and W_t1 (32x512) fp32 -> bf16 concat [160][512].
__global__ __launch_bounds__(256) void prep_kernel(
    const float* __restrict__ W_lin, const float* __restrict__ W_t1,
    __hip_bfloat16* __restrict__ wcat)
{
    int idx = blockIdx.x * 256 + threadIdx.x;
    if (idx < M_ * D_)       wcat[idx] = __float2bfloat16(W_lin[idx]);
    else if (idx < NT_ * D_) wcat[idx] = __float2bfloat16(W_t1[idx - M_ * D_]);
}

__global__ __launch_bounds__(256, 3) void main_kernel(
    const float* __restrict__ x, const float* __restrict__ mass,
    const float* __restrict__ ln_g, const float* __restrict__ ln_b,
    const float* __restrict__ b_lin, const float* __restrict__ W_t2,
    const float* __restrict__ b_t2, const __hip_bfloat16* __restrict__ wcat,
    float* __restrict__ out_tf, float* __restrict__ out_tit,
    float* __restrict__ part)
{
    __shared__ __align__(16) char lds[LDS_BYTES];
    char*  nxb   = lds + NX_OFF;
    float* out_l = reinterpret_cast<float*>(lds + NX_OFF);
    float* tau_l = reinterpret_cast<float*>(lds + TAU_OFF);

    const int tid  = threadIdx.x;
    const int lane = tid & 63;
    const int wave = tid >> 6;
    const int g0   = blockIdx.x * P_;        // first global point of block
    const int b_idx = g0 >> 16;              // batch index
    const int n0    = g0 & (NPTS_ - 1);

    // ---------------- Phase 1: HW-staged x -> LayerNorm -> bf16 nx in LDS ----------------
    // Wave w owns rows w*8 .. w*8+7. 4 rounds x 2 rows through a private 4 KB stage
    // buffer. global_load_lds issues are fire-and-forget (vmcnt-queued): 4 KB/wave in
    // flight, no barrier inside the phase -> waves/blocks de-sync and tile the HBM pipe.
    const int k0 = 4 * lane;
    const int k1 = 256 + 4 * lane;

    const float4 gv0 = *reinterpret_cast<const float4*>(ln_g + k0);
    const float4 gv1 = *reinterpret_cast<const float4*>(ln_g + k1);
    const float4 bv0 = *reinterpret_cast<const float4*>(ln_b + k0);
    const float4 bv1 = *reinterpret_cast<const float4*>(ln_b + k1);

    char* stw = lds + STAGE_OFF + wave * 4096;          // this wave's stage buffer
    const float* xg = x + (size_t)g0 * D_;

#define ISSUE_ROUND(t)                                                               \
    do {                                                                             \
        _Pragma("unroll")                                                            \
        for (int j = 0; j < 2; ++j) {                                                \
            const float* src = xg + (size_t)(wave * 8 + (t) * 2 + j) * D_ + k0;      \
            GLOAD_LDS(src,       stw + j * 2048);                                    \
            GLOAD_LDS(src + 256, stw + j * 2048 + 1024);                             \
        }                                                                            \
    } while (0)

    ISSUE_ROUND(0);

    #pragma unroll
    for (int t = 0; t < 4; ++t) {
        asm volatile("s_waitcnt vmcnt(0)" ::: "memory");   // this round's rows landed
        float4 v0[2], v1[2];
        #pragma unroll
        for (int j = 0; j < 2; ++j) {
            v0[j] = *reinterpret_cast<const float4*>(stw + j * 2048 + 16 * lane);
            v1[j] = *reinterpret_cast<const float4*>(stw + j * 2048 + 1024 + 16 * lane);
        }
        asm volatile("s_waitcnt lgkmcnt(0)" ::: "memory"); // reads retired: stage reusable
        if (t < 3) ISSUE_ROUND(t + 1);                     // next rows fly under LN compute

        #pragma unroll
        for (int j = 0; j < 2; ++j) {
            const int p = wave * 8 + t * 2 + j;
            float s = v0[j].x + v0[j].y + v0[j].z + v0[j].w
                    + v1[j].x + v1[j].y + v1[j].z + v1[j].w;
            float q = v0[j].x*v0[j].x + v0[j].y*v0[j].y + v0[j].z*v0[j].z + v0[j].w*v0[j].w
                    + v1[j].x*v1[j].x + v1[j].y*v1[j].y + v1[j].z*v1[j].z + v1[j].w*v1[j].w;
            #pragma unroll
            for (int off = 32; off >= 1; off >>= 1) {
                s += __shfl_xor(s, off);
                q += __shfl_xor(q, off);
            }
            const float mean = s * (1.0f / 512.0f);
            const float var  = q * (1.0f / 512.0f) - mean * mean;
            const float rstd = rsqrtf(var + 1e-5f);

            short4v pk0, pk1;
            pk0.x = bf16bits((v0[j].x - mean) * rstd * gv0.x + bv0.x);
            pk0.y = bf16bits((v0[j].y - mean) * rstd * gv0.y + bv0.y);
            pk0.z = bf16bits((v0[j].z - mean) * rstd * gv0.z + bv0.z);
            pk0.w = bf16bits((v0[j].w - mean) * rstd * gv0.w + bv0.w);
            pk1.x = bf16bits((v1[j].x - mean) * rstd * gv1.x + bv1.x);
            pk1.y = bf16bits((v1[j].y - mean) * rstd * gv1.y + bv1.y);
            pk1.z = bf16bits((v1[j].z - mean) * rstd * gv1.z + bv1.z);
            pk1.w = bf16bits((v1[j].w - mean) * rstd * gv1.w + bv1.w);
            // nx row p: 1024 B, XOR-swizzled (validated in round 2's GEMM)
            const int swp = (p & 7) << 4;
            const int c0  = 8 * lane;          // bytes of value k0
            const int c1  = 512 + 8 * lane;    // bytes of value k1
            *reinterpret_cast<short4v*>(nxb + p * 1024 + (c0 ^ swp)) = pk0;
            *reinterpret_cast<short4v*>(nxb + p * 1024 + (c1 ^ swp)) = pk1;
        }
    }
#undef ISSUE_ROUND
    __syncthreads();   // barrier 1: all nx rows ready

    // ---------------- Phase 2: MFMA GEMM, software-pipelined B frags from L2 ----------------
    const int pt   = wave >> 1;           // point tile: rows 0-15 / 16-31
    const int ncol = (wave & 1) * 80;     // col range: 0-79 or 80-159
    const int rrow = lane & 15;
    const int quad = lane >> 4;
    const int arow = pt * 16 + rrow;
    const int sw   = (arow & 7) << 4;

    f32x4 acc[5];
    #pragma unroll
    for (int i = 0; i < 5; ++i) acc[i] = (f32x4){0.f, 0.f, 0.f, 0.f};

    const short* wg   = reinterpret_cast<const short*>(wcat) + (ncol + rrow) * D_ + quad * 8;
    const char*  rowb = nxb + arow * 1024;

#define BLOAD(i, kt) (*reinterpret_cast<const bf16x8*>(wg + (i) * 16 * D_ + (kt) * 32))
#define ALOAD(kt)    (*reinterpret_cast<const bf16x8*>(rowb + ((quad * 16 + (kt) * 64) ^ sw)))

    bf16x8 b0[5], b1[5];
    #pragma unroll
    for (int i = 0; i < 5; ++i) b0[i] = BLOAD(i, 0);

    #pragma unroll
    for (int kp = 0; kp < 8; ++kp) {
        #pragma unroll
        for (int i = 0; i < 5; ++i) b1[i] = BLOAD(i, 2 * kp + 1);
        const bf16x8 a0 = ALOAD(2 * kp);
        #pragma unroll
        for (int i = 0; i < 5; ++i)
            acc[i] = __builtin_amdgcn_mfma_f32_16x16x32_bf16(a0, b0[i], acc[i], 0, 0, 0);
        if (kp < 7) {
            #pragma unroll
            for (int i = 0; i < 5; ++i) b0[i] = BLOAD(i, 2 * kp + 2);
        }
        const bf16x8 a1 = ALOAD(2 * kp + 1);
        #pragma unroll
        for (int i = 0; i < 5; ++i)
            acc[i] = __builtin_amdgcn_mfma_f32_16x16x32_bf16(a1, b1[i], acc[i], 0, 0, 0);
    }
#undef BLOAD
#undef ALOAD
    __syncthreads();   // barrier 2: all nx reads done; out_l may overwrite

    // spill accumulators: row = point, col = output index
    #pragma unroll
    for (int i = 0; i < 5; ++i) {
        #pragma unroll
        for (int r = 0; r < 4; ++r) {
            out_l[(pt * 16 + quad * 4 + r) * OPAD_ + ncol + i * 16 + rrow] = acc[i][r];
        }
    }
    __syncthreads();   // barrier 3: tile complete

    // ---------------- Phase 3a: temperature head (GELU exact -> softplus -> clamp) ----------------
    {
        const int p  = tid >> 3;
        const int j4 = (tid & 7) * 4;
        float s = 0.0f;
        #pragma unroll
        for (int jj = 0; jj < 4; ++jj) {
            const float hv = out_l[p * OPAD_ + M_ + j4 + jj];
            const float ge = 0.5f * hv * (1.0f + erff(hv * 0.70710678118f));
            s += ge * W_t2[j4 + jj];
        }
        s += __shfl_xor(s, 1);
        s += __shfl_xor(s, 2);
        s += __shfl_xor(s, 4);
        if ((tid & 7) == 0) {
            const float xx = s + b_t2[0];
            const float sp = fmaxf(xx, 0.0f) + log1pf(expf(-fabsf(xx)));
            tau_l[p] = fminf(fmaxf(sp, 0.01f), 3.0f);
        }
    }
    // no barrier: 3b's tau_l/out_l deps are wave-internal

    // ---------------- Phase 3b: softmax, 32 lanes per point (2 points/wave in flight) ----------------
    {
        const int half = lane >> 5;       // which point of the pair
        const int c    = lane & 31;       // mode subset: c, c+32, c+64, c+96
        float bl[4];
        #pragma unroll
        for (int j = 0; j < 4; ++j) bl[j] = b_lin[c + 32 * j];

        #pragma unroll
        for (int it = 0; it < 4; ++it) {
            const int p = wave * 8 + it * 2 + half;
            const int g = g0 + p;
            const float itau = 1.0f / tau_l[p];
            const float mv   = mass[g];
            float z[4];
            #pragma unroll
            for (int j = 0; j < 4; ++j)
                z[j] = (out_l[p * OPAD_ + c + 32 * j] + bl[j]) * itau;
            float mx = fmaxf(fmaxf(z[0], z[1]), fmaxf(z[2], z[3]));
            #pragma unroll
            for (int off = 16; off >= 1; off >>= 1) mx = fmaxf(mx, __shfl_xor(mx, off));
            float e[4];
            #pragma unroll
            for (int j = 0; j < 4; ++j) e[j] = __expf(z[j] - mx);
            float ss = (e[0] + e[1]) + (e[2] + e[3]);
            #pragma unroll
            for (int off = 16; off >= 1; off >>= 1) ss += __shfl_xor(ss, off);
            const float inv = 1.0f / ss;
            #pragma unroll
            for (int j = 0; j < 4; ++j) {
                const float t = e[j] * inv;
                out_tf[(size_t)g * M_ + c + 32 * j] = t;
                out_l[p * OPAD_ + c + 32 * j] = t * mv;
            }
        }
    }
    __syncthreads();   // barrier 4: tf*mass tile complete

    // ---------------- Phase 3c: transposed float4 writes of trial_in_t ----------------
    {
        const int mr = tid >> 3;          // 0..31: mode row within slab
        const int pg = tid & 7;           // point group: 4 consecutive points
        #pragma unroll
        for (int it = 0; it < 4; ++it) {
            const int m = it * 32 + mr;
            float4 v;
            v.x = out_l[(pg * 4 + 0) * OPAD_ + m];
            v.y = out_l[(pg * 4 + 1) * OPAD_ + m];
            v.z = out_l[(pg * 4 + 2) * OPAD_ + m];
            v.w = out_l[(pg * 4 + 3) * OPAD_ + m];
            *reinterpret_cast<float4*>(
                out_tit + (size_t)b_idx * M_ * NPTS_ + (size_t)m * NPTS_ + n0 + pg * 4) = v;
        }
    }

    // ---------------- Phase 3d: per-block column sums -> workspace partials ----------------
    if (tid < M_) {
        float s = 0.0f;
        #pragma unroll
        for (int p = 0; p < P_; ++p) s += out_l[p * OPAD_ + tid];
        part[((size_t)(b_idx * M_ + tid)) * BLKS_PER_B + (blockIdx.x & (BLKS_PER_B - 1))] = s;
    }
}

// Reduce partials: one block per (b,m); 2048 partials each.
__global__ __launch_bounds__(256) void finish_kernel(
    const float* __restrict__ part, float* __restrict__ out_inv)
{
    __shared__ float wsum[4];
    const int j = blockIdx.x;           // b*128 + m
    const int t = threadIdx.x;
    const float* row = part + (size_t)j * BLKS_PER_B;
    float s = 0.0f;
    #pragma unroll
    for (int i = 0; i < 8; ++i) s += row[i * 256 + t];
    #pragma unroll
    for (int off = 32; off >= 1; off >>= 1) s += __shfl_xor(s, off);
    if ((t & 63) == 0) wsum[t >> 6] = s;
    __syncthreads();
    if (t == 0) out_inv[j] = 1.0f / (wsum[0] + wsum[1] + wsum[2] + wsum[3] + 1e-6f);
}

extern "C" void kernel_launch(void* const* d_in, const int* in_sizes, int n_in,
                              void* d_out, int out_size, void* d_ws, size_t ws_size,
                              hipStream_t stream) {
    const float* x     = (const float*)d_in[0];
    const float* mass  = (const float*)d_in[1];
    const float* ln_g  = (const float*)d_in[2];
    const float* ln_b  = (const float*)d_in[3];
    const float* W_lin = (const float*)d_in[4];
    const float* b_lin = (const float*)d_in[5];
    const float* W_t1  = (const float*)d_in[6];
    const float* W_t2  = (const float*)d_in[7];
    const float* b_t2  = (const float*)d_in[8];

    __hip_bfloat16* wcat = (__hip_bfloat16*)d_ws;                    // 163,840 B
    float* part          = (float*)((char*)d_ws + NT_ * D_ * 2);     // 2*128*2048 floats = 2 MB

    float* out_tf  = (float*)d_out;                                  // (B,N,M)
    float* out_tit = out_tf + (size_t)2 * NPTS_ * M_;                // (B,M,N)
    float* out_inv = out_tit + (size_t)2 * NPTS_ * M_;               // (B,M,1)

    prep_kernel<<<(NT_ * D_ + 255) / 256, 256, 0, stream>>>(W_lin, W_t1, wcat);

    const int nblocks = (2 * NPTS_) / P_;   // 4096
    main_kernel<<<nblocks, 256, 0, stream>>>(x, mass, ln_g, ln_b, b_lin, W_t2, b_t2,
                                             wcat, out_tf, out_tit, part);

    finish_kernel<<<2 * M_, 256, 0, stream>>>(part, out_inv);
}